// Round 8
// baseline (385.228 us; speedup 1.0000x reference)
//
#include <hip/hip_runtime.h>
#include <math.h>

#define EPSB 1e-5f

constexpr int B_ = 4;
constexpr int C_ = 64;
constexpr int H_ = 160;
constexpr int W_ = 160;
constexpr int HW_ = H_ * W_;

// workspace layout (float offsets)
constexpr size_t X_OFF   = 0;                                    // x NHWC bf16 in lower half; O bf16 in upper half
constexpr size_t Y1_OFF  = X_OFF  + (size_t)B_ * HW_ * 64;       // y1 NHWC @80x80 (fp32)
constexpr size_t Y2_OFF  = Y1_OFF + (size_t)B_ * 6400 * 64;      // y2 NHWC @40x40
constexpr size_t Y3_OFF  = Y2_OFF + (size_t)B_ * 1600 * 64;      // y3 NHWC @20x20
constexpr size_t OM_OFF  = Y3_OFF + (size_t)B_ * 400 * 64;       // (unused)
constexpr size_t WR0_OFF = OM_OFF + (size_t)B_ * HW_ * 27;       // w0 fp32 [ci][o]: 4096
constexpr size_t WTB_OFF = WR0_OFF + 4096;                       // dcn_w bf16 [k][o][c pad72]: 41472 ush
constexpr size_t RWB_OFF = WTB_OFF + (9 * 64 * 72) / 2;          // off_w bf16 [tap][o pad32][ci]: 18432 ush
constexpr size_t SB_OFF  = RWB_OFF + (9 * 32 * 64) / 2;          // 5 BNs x (scale[64], bias[64])
// transposed conv1x1 weights OVERLAID at head of X region (die before fuse2 writes x).
constexpr size_t WR1_OFF = X_OFF + 0;       // w1 fp32 [ci][o]
constexpr size_t WR2_OFF = X_OFF + 8192;    // w2 fp32 [ci][o]
constexpr size_t WR3_OFF = X_OFF + 24576;   // w3 fp32 [ci][o]
// ushort offsets within the X float-region (B_*HW_*64 floats = 13,107,200 ushorts):
//   x bf16: [0, 6553600)   O bf16: [6553600, 13107200)
constexpr size_t XU_X = 0;
constexpr size_t XU_O = 6553600;

typedef short bf16x8 __attribute__((ext_vector_type(8)));
typedef float f32x4 __attribute__((ext_vector_type(4)));
typedef unsigned int u32x2 __attribute__((ext_vector_type(2)));

static __device__ __forceinline__ unsigned short f2bf(float f) {
    unsigned int u = __float_as_uint(f);
    u += 0x7fff + ((u >> 16) & 1);   // RNE
    return (unsigned short)(u >> 16);
}
static __device__ __forceinline__ float bf2f(unsigned short s) {
    return __uint_as_float((unsigned int)s << 16);
}

__global__ __launch_bounds__(256) void prep_kernel(
    const float* __restrict__ g0, const float* __restrict__ b0, const float* __restrict__ m0, const float* __restrict__ v0,
    const float* __restrict__ g1, const float* __restrict__ b1, const float* __restrict__ m1, const float* __restrict__ v1,
    const float* __restrict__ g2, const float* __restrict__ b2, const float* __restrict__ m2, const float* __restrict__ v2,
    const float* __restrict__ g3, const float* __restrict__ b3, const float* __restrict__ m3, const float* __restrict__ v3,
    const float* __restrict__ gf, const float* __restrict__ bf, const float* __restrict__ mf, const float* __restrict__ vf,
    const float* __restrict__ w0, const float* __restrict__ w1, const float* __restrict__ w2, const float* __restrict__ w3,
    const float* __restrict__ dcn_w, const float* __restrict__ off_w,
    float* __restrict__ ws)
{
    int tid = blockIdx.x * 256 + threadIdx.x;
    if (tid < 320) {  // BN scale/bias fold
        int j = tid >> 6, c = tid & 63;
        const float *g, *b, *m, *v;
        switch (j) {
            case 0: g = g0; b = b0; m = m0; v = v0; break;
            case 1: g = g1; b = b1; m = m1; v = v1; break;
            case 2: g = g2; b = b2; m = m2; v = v2; break;
            case 3: g = g3; b = b3; m = m3; v = v3; break;
            default: g = gf; b = bf; m = mf; v = vf; break;
        }
        float sc = g[c] * rsqrtf(v[c] + EPSB);
        ws[SB_OFF + j * 128 + c]      = sc;
        ws[SB_OFF + j * 128 + 64 + c] = b[c] - m[c] * sc;
        return;
    }
    int t = tid - 320;
    if (t < 4096) {  // wr0[ci*64+o] = w0[o*64+ci]
        int ci = t >> 6, o = t & 63;
        ws[WR0_OFF + t] = w0[o * 64 + ci];
        return;
    }
    t -= 4096;
    if (t < 9 * 64 * 72) {  // wtb[k][o][c pad72] bf16 = dcn_w[o][c][k]
        int k = t / 4608, r = t % 4608, o = r / 72, c = r % 72;
        float v = (c < 64) ? dcn_w[o * 576 + c * 9 + k] : 0.f;
        ((unsigned short*)(ws + WTB_OFF))[t] = f2bf(v);
        return;
    }
    t -= 9 * 64 * 72;
    if (t < 9 * 32 * 64) {  // rwb[tap][o pad32][ci] bf16 = off_w[o][ci][tap]
        int tap = t >> 11, r = t & 2047, o = r >> 6, ci = r & 63;
        float v = (o < 27) ? off_w[o * 576 + ci * 9 + tap] : 0.f;
        ((unsigned short*)(ws + RWB_OFF))[t] = f2bf(v);
        return;
    }
    t -= 9 * 32 * 64;
    if (t < 8192) {  // wr1[ci*64+o] = w1[o*128+ci]
        int ci = t >> 6, o = t & 63;
        ws[WR1_OFF + t] = w1[o * 128 + ci];
        return;
    }
    t -= 8192;
    if (t < 16384) {  // wr2
        int ci = t >> 6, o = t & 63;
        ws[WR2_OFF + t] = w2[o * 256 + ci];
        return;
    }
    t -= 16384;
    if (t < 32768) {  // wr3
        int ci = t >> 6, o = t & 63;
        ws[WR3_OFF + t] = w3[o * 512 + ci];
        return;
    }
}

// produce: conv1x1+BN for f1/f2/f3 (blocks 0..524) MERGED with conv1x1(f0)+BN -> O bf16
// (blocks 525..2124). 2125 blocks co-resident: the 1600 fuse1 blocks hide the conv blocks'
// latency chains and f2/f3 tail (old conv_all ran at 2 blocks/CU). LDS union 16.6 KB.
__global__ __launch_bounds__(256) void produce_kernel(
    const float* __restrict__ f0in, const float* __restrict__ f1in,
    const float* __restrict__ f2in, const float* __restrict__ f3in,
    float* __restrict__ ws)
{
    __shared__ __align__(16) unsigned char SM[16640];

    int blk = blockIdx.x;
    int tid  = threadIdx.x;
    int lane = tid & 63;

    if (blk < 525) {
        // ===== conv role: y = BN(conv1x1(f)) fp32, single-R0 tree reduce =====
        float* R0 = (float*)SM;   // [64][65]
        const float* fin; const float* wr; const float* sbg; float* yout;
        int Cin, hw, tile;
        if (blk < 400)      { fin = f1in; wr = ws + WR1_OFF; sbg = ws + SB_OFF + 128; yout = ws + Y1_OFF; Cin = 128; hw = 6400; tile = blk; }
        else if (blk < 500) { fin = f2in; wr = ws + WR2_OFF; sbg = ws + SB_OFF + 256; yout = ws + Y2_OFF; Cin = 256; hw = 1600; tile = blk - 400; }
        else                { fin = f3in; wr = ws + WR3_OFF; sbg = ws + SB_OFF + 384; yout = ws + Y3_OFF; Cin = 512; hw = 400;  tile = blk - 500; }

        int wv = __builtin_amdgcn_readfirstlane(tid >> 6);

        int P = tile * 64 + lane;
        int b = P / hw;
        int p = P - b * hw;

        int cq = Cin >> 2;
        const float* fb = fin + ((size_t)b * Cin + (size_t)wv * cq) * hw + p;
        const float* wq = wr + (wv * cq) * 64;

        float acc[64];
#pragma unroll
        for (int o = 0; o < 64; o++) acc[o] = 0.f;

        for (int c0 = 0; c0 < cq; c0 += 8) {
            float fv[8];
#pragma unroll
            for (int j = 0; j < 8; j++) fv[j] = fb[(size_t)(c0 + j) * hw];
#pragma unroll
            for (int j = 0; j < 8; j++) {
                const float* wrow = wq + (c0 + j) * 64;
#pragma unroll
                for (int o = 0; o < 64; o++) acc[o] = fmaf(fv[j], wrow[o], acc[o]);
            }
        }

        // single-buffer tree reduce: (0+2), (1+3), then 0 += sum13, BN, stage in R0
        if (wv == 2) {
#pragma unroll
            for (int o = 0; o < 64; o++) R0[lane * 65 + o] = acc[o];
        }
        __syncthreads();
        if (wv == 0) {
#pragma unroll
            for (int o = 0; o < 64; o++) acc[o] += R0[lane * 65 + o];
        }
        __syncthreads();
        if (wv == 3) {
#pragma unroll
            for (int o = 0; o < 64; o++) R0[lane * 65 + o] = acc[o];
        }
        __syncthreads();
        if (wv == 1) {
#pragma unroll
            for (int o = 0; o < 64; o++) acc[o] += R0[lane * 65 + o];
        }
        __syncthreads();
        if (wv == 1) {
#pragma unroll
            for (int o = 0; o < 64; o++) R0[lane * 65 + o] = acc[o];
        }
        __syncthreads();
        if (wv == 0) {
#pragma unroll
            for (int o = 0; o < 64; o++) {
                float v = acc[o] + R0[lane * 65 + o];
                R0[lane * 65 + o] = fmaf(v, sbg[o], sbg[64 + o]);
            }
        }
        __syncthreads();

#pragma unroll
        for (int it = 0; it < 16; it++) {
            int idx = it * 256 + tid;
            int px = idx >> 6, o = idx & 63;
            yout[(size_t)(tile * 64 + px) * 64 + o] = R0[px * 65 + o];
        }
    } else {
        // ===== fuse1 role: O = BN(conv1x1(f0)) bf16 NHWC =====
        unsigned short* Ot = (unsigned short*)SM;   // [64][68] ushort = 8.7 KB
        int fblk = blk - 525;
        int xcd = fblk & 7, slot = fblk >> 3;
        int b = xcd >> 1;
        int t = (xcd & 1) * 200 + slot;
        int p0 = t * 64;
        int cb = __builtin_amdgcn_readfirstlane(tid >> 6);
        int p = p0 + lane;
        const float* wr0 = ws + WR0_OFF + cb * 16;
        const float* sb  = ws + SB_OFF;  // bn0

        float acc[16];
#pragma unroll
        for (int i = 0; i < 16; i++) acc[i] = 0.f;

        const float* f0b = f0in + (size_t)b * 64 * HW_ + p;
        for (int ci0 = 0; ci0 < 64; ci0 += 8) {
            float fv[8];
#pragma unroll
            for (int j = 0; j < 8; j++) fv[j] = f0b[(size_t)(ci0 + j) * HW_];
#pragma unroll
            for (int j = 0; j < 8; j++) {
                const float* wrow = wr0 + (ci0 + j) * 64;
#pragma unroll
                for (int i = 0; i < 16; i++) acc[i] = fmaf(fv[j], wrow[i], acc[i]);
            }
        }
        unsigned short* orow = Ot + lane * 68 + cb * 16;
#pragma unroll
        for (int i = 0; i < 16; i++) {
            int o = cb * 16 + i;
            orow[i] = f2bf(fmaf(acc[i], sb[o], sb[64 + o]));
        }
        __syncthreads();

        // coalesced O store: 8 iters x 256 thr x 4B
        unsigned short* Ob = (unsigned short*)ws + XU_O + ((size_t)b * HW_ + p0) * 64;
#pragma unroll
        for (int it = 0; it < 8; it++) {
            int idx = it * 256 + tid;
            int px = idx >> 5, seg = idx & 31;
            *(unsigned int*)(Ob + (size_t)px * 64 + seg * 2) =
                *(const unsigned int*)(Ot + px * 68 + seg * 2);
        }
    }
}

// fuse2: x = relu(O + up2(y1) + up4(y2) + up8(y3)) stored NHWC bf16. Barrier-free, no LDS.
__global__ __launch_bounds__(256) void fuse2_kernel(float* __restrict__ ws)
{
    int tid = threadIdx.x;
    int blk = blockIdx.x;
    int xcd = blk & 7, slot = blk >> 3;
    int b = xcd >> 1;
    int t = (xcd & 1) * 200 + slot;
    int p0 = t * 64;
    int lane = tid & 63;
    int cb = __builtin_amdgcn_readfirstlane(tid >> 6);
    int chunk = lane & 15, pxo = lane >> 4;

    const unsigned short* Ob = (const unsigned short*)ws + XU_O + ((size_t)b * HW_ + p0) * 64;
    unsigned short* xb = (unsigned short*)ws + XU_X + ((size_t)b * HW_ + p0) * 64;

#pragma unroll
    for (int r = 0; r < 4; r++) {
        int gpx = cb * 16 + r * 4 + pxo;
        int gp = p0 + gpx;
        int h = gp / W_, w = gp % W_;

        float fy1 = h * (79.f / 159.f); int i1 = (int)fy1; if (i1 > 78) i1 = 78; float ty1 = fy1 - i1;
        float fx1 = w * (79.f / 159.f); int j1 = (int)fx1; if (j1 > 78) j1 = 78; float tx1 = fx1 - j1;
        const float* y1 = ws + Y1_OFF + ((size_t)b * 6400 + (size_t)(i1 * 80 + j1)) * 64 + chunk * 4;
        float fy2 = h * (39.f / 159.f); int i2 = (int)fy2; if (i2 > 38) i2 = 38; float ty2 = fy2 - i2;
        float fx2 = w * (39.f / 159.f); int j2 = (int)fx2; if (j2 > 38) j2 = 38; float tx2 = fx2 - j2;
        const float* y2 = ws + Y2_OFF + ((size_t)b * 1600 + (size_t)(i2 * 40 + j2)) * 64 + chunk * 4;
        float fy3 = h * (19.f / 159.f); int i3 = (int)fy3; if (i3 > 18) i3 = 18; float ty3 = fy3 - i3;
        float fx3 = w * (19.f / 159.f); int j3 = (int)fx3; if (j3 > 18) j3 = 18; float tx3 = fx3 - j3;
        const float* y3 = ws + Y3_OFF + ((size_t)b * 400 + (size_t)(i3 * 20 + j3)) * 64 + chunk * 4;

        f32x4 A[12];
        A[0]  = *(const f32x4*)(y1);
        A[1]  = *(const f32x4*)(y1 + 64);
        A[2]  = *(const f32x4*)(y1 + 80 * 64);
        A[3]  = *(const f32x4*)(y1 + 81 * 64);
        A[4]  = *(const f32x4*)(y2);
        A[5]  = *(const f32x4*)(y2 + 64);
        A[6]  = *(const f32x4*)(y2 + 40 * 64);
        A[7]  = *(const f32x4*)(y2 + 41 * 64);
        A[8]  = *(const f32x4*)(y3);
        A[9]  = *(const f32x4*)(y3 + 64);
        A[10] = *(const f32x4*)(y3 + 20 * 64);
        A[11] = *(const f32x4*)(y3 + 21 * 64);

        u32x2 ov = *(const u32x2*)(Ob + (size_t)gpx * 64 + chunk * 4);
        f32x4 v;
        v[0] = bf2f((unsigned short)(ov.x & 0xffff));
        v[1] = bf2f((unsigned short)(ov.x >> 16));
        v[2] = bf2f((unsigned short)(ov.y & 0xffff));
        v[3] = bf2f((unsigned short)(ov.y >> 16));

        float w00, w01, w10, w11;
        w00 = (1.f - ty1) * (1.f - tx1); w01 = (1.f - ty1) * tx1; w10 = ty1 * (1.f - tx1); w11 = ty1 * tx1;
#pragma unroll
        for (int j = 0; j < 4; j++)
            v[j] += A[0][j] * w00 + A[1][j] * w01 + A[2][j] * w10 + A[3][j] * w11;
        w00 = (1.f - ty2) * (1.f - tx2); w01 = (1.f - ty2) * tx2; w10 = ty2 * (1.f - tx2); w11 = ty2 * tx2;
#pragma unroll
        for (int j = 0; j < 4; j++)
            v[j] += A[4][j] * w00 + A[5][j] * w01 + A[6][j] * w10 + A[7][j] * w11;
        w00 = (1.f - ty3) * (1.f - tx3); w01 = (1.f - ty3) * tx3; w10 = ty3 * (1.f - tx3); w11 = ty3 * tx3;
#pragma unroll
        for (int j = 0; j < 4; j++)
            v[j] += A[8][j] * w00 + A[9][j] * w01 + A[10][j] * w10 + A[11][j] * w11;

#pragma unroll
        for (int j = 0; j < 4; j++) v[j] = fmaxf(v[j], 0.f);
        unsigned int lo = ((unsigned int)f2bf(v[1]) << 16) | f2bf(v[0]);
        unsigned int hi = ((unsigned int)f2bf(v[3]) << 16) | f2bf(v[2]);
        *(u32x2*)(xb + (size_t)gpx * 64 + chunk * 4) = (u32x2){lo, hi};
    }
}

// FUSED offconv + dcn, x read as bf16 NHWC (unchanged from round 7 — control).
__global__ __launch_bounds__(256, 8) void dcn_fused_kernel(const float* __restrict__ off_b,
                                                           float* __restrict__ ws, float* __restrict__ out)
{
    __shared__ __align__(16) unsigned char SMEM[16640];
    unsigned short* A  = (unsigned short*)SMEM;        // 9216 B
    float*          OMs = (float*)(SMEM + 9216);       // 6912 B

    int tid = threadIdx.x;
    int blk = blockIdx.x;
    int xcd = blk & 7, slot = blk >> 3;
    int b = xcd >> 1;
    int t = (xcd & 1) * 200 + slot;
    int p0 = t * 64;
    int lane = tid & 63, cb = tid >> 6;
    int px = lane;
    int p = p0 + px;
    int h = p / W_, w = p % W_;
    int mrow = lane & 15, quad = lane >> 4;
    int chunk = lane & 15, pxo = lane >> 4;

    const unsigned short* rwb = (const unsigned short*)(ws + RWB_OFF);
    const unsigned short* wtb = (const unsigned short*)(ws + WTB_OFF);
    const unsigned short* xbh = (const unsigned short*)ws + XU_X + (size_t)b * HW_ * 64;
    const float* sb = ws + SB_OFF + 4 * 128;

    // ============ phase 1: offset/mask 3x3 conv ============
    {
        f32x4 acc2[2];
        acc2[0] = (f32x4){0.f, 0.f, 0.f, 0.f};
        acc2[1] = (f32x4){0.f, 0.f, 0.f, 0.f};

        for (int tap = 0; tap < 9; ++tap) {
            int dy = tap / 3 - 1, dx = tap % 3 - 1;
            int delta = dy * W_ + dx;
            int  pss[4];
            bool vlds[4];
#pragma unroll
            for (int r = 0; r < 4; r++) {
                int gpx = cb * 16 + r * 4 + pxo;
                int gp = p0 + gpx;
                int gh = gp / W_, gw = gp % W_;
                int yy = gh + dy, xx = gw + dx;
                vlds[r] = (yy >= 0) && (yy < H_) && (xx >= 0) && (xx < W_);
                int ps = gp + delta;
                pss[r] = min(max(ps, 0), HW_ - 1);
            }
            u32x2 g[4];
#pragma unroll
            for (int r = 0; r < 4; r++)
                g[r] = *(const u32x2*)(xbh + (size_t)pss[r] * 64 + chunk * 4);
#pragma unroll
            for (int r = 0; r < 4; r++) {
                int gpx = cb * 16 + r * 4 + pxo;
                u32x2 gv;
                gv.x = vlds[r] ? g[r].x : 0u;
                gv.y = vlds[r] ? g[r].y : 0u;
                *(u32x2*)(A + gpx * 72 + chunk * 4) = gv;
            }

            const unsigned short* Ab = A + (cb * 16 + mrow) * 72;
#pragma unroll
            for (int ks = 0; ks < 2; ks++) {
                bf16x8 af = *(const bf16x8*)(Ab + ks * 32 + quad * 8);
#pragma unroll
                for (int nt = 0; nt < 2; nt++) {
                    bf16x8 bf_ = *(const bf16x8*)(rwb + tap * 2048 + (nt * 16 + mrow) * 64 + ks * 32 + quad * 8);
                    acc2[nt] = __builtin_amdgcn_mfma_f32_16x16x32_bf16(af, bf_, acc2[nt], 0, 0, 0);
                }
            }
        }

        __syncthreads();
        float* Cl = (float*)SMEM;  // [64 px][28]
#pragma unroll
        for (int nt = 0; nt < 2; nt++) {
            int o = nt * 16 + mrow;
            if (o < 27) {
                int pr = cb * 16 + quad * 4;
#pragma unroll
                for (int r = 0; r < 4; r++) Cl[(pr + r) * 28 + o] = acc2[nt][r];
            }
        }
        __syncthreads();

        for (int k = cb; k < 9; k += 4) {
            float ady = Cl[px * 28 + 2 * k]     + off_b[2 * k];
            float adx = Cl[px * 28 + 2 * k + 1] + off_b[2 * k + 1];
            float am  = Cl[px * 28 + 18 + k]    + off_b[18 + k];
            float sy = (float)(h + k / 3 - 1) + ady;
            float sx = (float)(w + k % 3 - 1) + adx;
            float mk = 1.f / (1.f + __expf(-am));
            OMs[px * 27 + 3 * k]     = sy;
            OMs[px * 27 + 3 * k + 1] = sx;
            OMs[px * 27 + 3 * k + 2] = mk;
        }
        __syncthreads();
    }

    // ============ phase 2: modulated deformable conv ============
    f32x4 acc[4];
#pragma unroll
    for (int nt = 0; nt < 4; nt++) acc[nt] = (f32x4){0.f, 0.f, 0.f, 0.f};

    for (int k = 0; k < 9; ++k) {
#pragma unroll
        for (int rp = 0; rp < 2; rp++) {
            int   idxs[2][4];
            float wvs[2][4];
#pragma unroll
            for (int rr = 0; rr < 2; rr++) {
                int r = rp * 2 + rr;
                int gpx = cb * 16 + r * 4 + pxo;
                float sy = OMs[gpx * 27 + 3 * k];
                float sx = OMs[gpx * 27 + 3 * k + 1];
                float mk = OMs[gpx * 27 + 3 * k + 2];
                float y0f = floorf(sy), x0f = floorf(sx);
                int y0 = (int)y0f, x0 = (int)x0f;
                float ty = sy - y0f, tx = sx - x0f;
#pragma unroll
                for (int cr = 0; cr < 4; cr++) {
                    int dy = cr >> 1, dx = cr & 1;
                    int yy = y0 + dy, xx = x0 + dx;
                    float wy = dy ? ty : 1.f - ty;
                    float wx = dx ? tx : 1.f - tx;
                    bool vld = (yy >= 0) && (yy < H_) && (xx >= 0) && (xx < W_);
                    int yc = min(max(yy, 0), H_ - 1);
                    int xc = min(max(xx, 0), W_ - 1);
                    idxs[rr][cr] = yc * W_ + xc;
                    wvs[rr][cr]  = vld ? wy * wx * mk : 0.f;
                }
            }
            u32x2 g[2][4];
#pragma unroll
            for (int rr = 0; rr < 2; rr++)
#pragma unroll
                for (int cr = 0; cr < 4; cr++)
                    g[rr][cr] = *(const u32x2*)(xbh + (size_t)idxs[rr][cr] * 64 + chunk * 4);
#pragma unroll
            for (int rr = 0; rr < 2; rr++) {
                int r = rp * 2 + rr;
                int gpx = cb * 16 + r * 4 + pxo;
                f32x4 v = (f32x4){0.f, 0.f, 0.f, 0.f};
#pragma unroll
                for (int cr = 0; cr < 4; cr++) {
                    float wv = wvs[rr][cr];
                    float e0 = __uint_as_float(g[rr][cr].x << 16);
                    float e1 = __uint_as_float(g[rr][cr].x & 0xffff0000u);
                    float e2 = __uint_as_float(g[rr][cr].y << 16);
                    float e3 = __uint_as_float(g[rr][cr].y & 0xffff0000u);
                    v[0] = fmaf(e0, wv, v[0]);
                    v[1] = fmaf(e1, wv, v[1]);
                    v[2] = fmaf(e2, wv, v[2]);
                    v[3] = fmaf(e3, wv, v[3]);
                }
                unsigned int lo = ((unsigned int)f2bf(v[1]) << 16) | f2bf(v[0]);
                unsigned int hi = ((unsigned int)f2bf(v[3]) << 16) | f2bf(v[2]);
                *(u32x2*)(A + gpx * 72 + chunk * 4) = (u32x2){lo, hi};
            }
        }

        const unsigned short* Ab = A + (cb * 16 + mrow) * 72;
#pragma unroll
        for (int ks = 0; ks < 2; ks++) {
            bf16x8 af = *(const bf16x8*)(Ab + ks * 32 + quad * 8);
#pragma unroll
            for (int nt = 0; nt < 4; nt++) {
                bf16x8 bf_ = *(const bf16x8*)(wtb + k * 4608 + (nt * 16 + mrow) * 72 + ks * 32 + quad * 8);
                acc[nt] = __builtin_amdgcn_mfma_f32_16x16x32_bf16(af, bf_, acc[nt], 0, 0, 0);
            }
        }
    }

    __syncthreads();
    float* C_lds = (float*)SMEM;
#pragma unroll
    for (int nt = 0; nt < 4; nt++) {
        int o = nt * 16 + mrow;
        int pxb = cb * 16 + quad * 4;
#pragma unroll
        for (int r = 0; r < 4; r++) C_lds[o * 65 + pxb + r] = acc[nt][r];
    }
    __syncthreads();
#pragma unroll
    for (int i = 0; i < 16; i++) {
        int o = cb * 16 + i;
        float v = C_lds[o * 65 + lane];
        v = fmaf(v, sb[o], sb[64 + o]);
        out[((size_t)b * 64 + o) * HW_ + p0 + lane] = fmaxf(v, 0.f);
    }
}

extern "C" void kernel_launch(void* const* d_in, const int* in_sizes, int n_in,
                              void* d_out, int out_size, void* d_ws, size_t ws_size,
                              hipStream_t stream)
{
    const float* f0 = (const float*)d_in[0];
    const float* f1 = (const float*)d_in[1];
    const float* f2 = (const float*)d_in[2];
    const float* f3 = (const float*)d_in[3];
    const float* w0 = (const float*)d_in[4];
    const float* g0 = (const float*)d_in[5];
    const float* b0 = (const float*)d_in[6];
    const float* m0 = (const float*)d_in[7];
    const float* v0 = (const float*)d_in[8];
    const float* w1 = (const float*)d_in[9];
    const float* g1 = (const float*)d_in[10];
    const float* b1 = (const float*)d_in[11];
    const float* m1 = (const float*)d_in[12];
    const float* v1 = (const float*)d_in[13];
    const float* w2 = (const float*)d_in[14];
    const float* g2 = (const float*)d_in[15];
    const float* b2 = (const float*)d_in[16];
    const float* m2 = (const float*)d_in[17];
    const float* v2 = (const float*)d_in[18];
    const float* w3 = (const float*)d_in[19];
    const float* g3 = (const float*)d_in[20];
    const float* b3 = (const float*)d_in[21];
    const float* m3 = (const float*)d_in[22];
    const float* v3 = (const float*)d_in[23];
    const float* off_w = (const float*)d_in[24];
    const float* off_b = (const float*)d_in[25];
    const float* dcn_w = (const float*)d_in[26];
    const float* gf = (const float*)d_in[27];
    const float* bf = (const float*)d_in[28];
    const float* mf = (const float*)d_in[29];
    const float* vf = (const float*)d_in[30];

    float* ws  = (float*)d_ws;
    float* out = (float*)d_out;

    prep_kernel<<<dim3(476), dim3(256), 0, stream>>>(
        g0, b0, m0, v0, g1, b1, m1, v1, g2, b2, m2, v2, g3, b3, m3, v3,
        gf, bf, mf, vf, w0, w1, w2, w3, dcn_w, off_w, ws);

    produce_kernel<<<dim3(2125), dim3(256), 0, stream>>>(f0, f1, f2, f3, ws);

    fuse2_kernel<<<dim3(1600), dim3(256), 0, stream>>>(ws);

    dcn_fused_kernel<<<dim3(1600), dim3(256), 0, stream>>>(off_b, ws, out);
}

// Round 9
// 323.516 us; speedup vs baseline: 1.1908x; 1.1908x over previous
//
#include <hip/hip_runtime.h>
#include <math.h>

#define EPSB 1e-5f

constexpr int B_ = 4;
constexpr int C_ = 64;
constexpr int H_ = 160;
constexpr int W_ = 160;
constexpr int HW_ = H_ * W_;

// workspace layout (float offsets)
constexpr size_t X_OFF   = 0;                                    // x NHWC bf16: [b][p][64] (half the region)
constexpr size_t Y1_OFF  = X_OFF  + (size_t)B_ * HW_ * 64;       // y1 NHWC @80x80 (fp32)
constexpr size_t Y2_OFF  = Y1_OFF + (size_t)B_ * 6400 * 64;      // y2 NHWC @40x40
constexpr size_t Y3_OFF  = Y2_OFF + (size_t)B_ * 1600 * 64;      // y3 NHWC @20x20
constexpr size_t OM_OFF  = Y3_OFF + (size_t)B_ * 400 * 64;       // (unused)
constexpr size_t WR0_OFF = OM_OFF + (size_t)B_ * HW_ * 27;       // w0 fp32 [ci][o]: 4096
constexpr size_t WTB_OFF = WR0_OFF + 4096;                       // dcn_w bf16 [k][o][c pad72]: 41472 ush
constexpr size_t RWB_OFF = WTB_OFF + (9 * 64 * 72) / 2;          // off_w bf16 [tap][o pad32][ci]: 18432 ush
constexpr size_t SB_OFF  = RWB_OFF + (9 * 32 * 64) / 2;          // 5 BNs x (scale[64], bias[64])
// transposed conv1x1 weights OVERLAID at head of X region (die before fuse writes x).
constexpr size_t WR1_OFF = X_OFF + 0;       // w1 fp32 [ci][o]
constexpr size_t WR2_OFF = X_OFF + 8192;    // w2 fp32 [ci][o]
constexpr size_t WR3_OFF = X_OFF + 24576;   // w3 fp32 [ci][o]

typedef short bf16x8 __attribute__((ext_vector_type(8)));
typedef float f32x4 __attribute__((ext_vector_type(4)));
typedef unsigned int u32x2 __attribute__((ext_vector_type(2)));

static __device__ __forceinline__ unsigned short f2bf(float f) {
    unsigned int u = __float_as_uint(f);
    u += 0x7fff + ((u >> 16) & 1);   // RNE
    return (unsigned short)(u >> 16);
}

__global__ __launch_bounds__(256) void prep_kernel(
    const float* __restrict__ g0, const float* __restrict__ b0, const float* __restrict__ m0, const float* __restrict__ v0,
    const float* __restrict__ g1, const float* __restrict__ b1, const float* __restrict__ m1, const float* __restrict__ v1,
    const float* __restrict__ g2, const float* __restrict__ b2, const float* __restrict__ m2, const float* __restrict__ v2,
    const float* __restrict__ g3, const float* __restrict__ b3, const float* __restrict__ m3, const float* __restrict__ v3,
    const float* __restrict__ gf, const float* __restrict__ bf, const float* __restrict__ mf, const float* __restrict__ vf,
    const float* __restrict__ w0, const float* __restrict__ w1, const float* __restrict__ w2, const float* __restrict__ w3,
    const float* __restrict__ dcn_w, const float* __restrict__ off_w,
    float* __restrict__ ws)
{
    int tid = blockIdx.x * 256 + threadIdx.x;
    if (tid < 320) {  // BN scale/bias fold
        int j = tid >> 6, c = tid & 63;
        const float *g, *b, *m, *v;
        switch (j) {
            case 0: g = g0; b = b0; m = m0; v = v0; break;
            case 1: g = g1; b = b1; m = m1; v = v1; break;
            case 2: g = g2; b = b2; m = m2; v = v2; break;
            case 3: g = g3; b = b3; m = m3; v = v3; break;
            default: g = gf; b = bf; m = mf; v = vf; break;
        }
        float sc = g[c] * rsqrtf(v[c] + EPSB);
        ws[SB_OFF + j * 128 + c]      = sc;
        ws[SB_OFF + j * 128 + 64 + c] = b[c] - m[c] * sc;
        return;
    }
    int t = tid - 320;
    if (t < 4096) {  // wr0[ci*64+o] = w0[o*64+ci]
        int ci = t >> 6, o = t & 63;
        ws[WR0_OFF + t] = w0[o * 64 + ci];
        return;
    }
    t -= 4096;
    if (t < 9 * 64 * 72) {  // wtb[k][o][c pad72] bf16 = dcn_w[o][c][k]
        int k = t / 4608, r = t % 4608, o = r / 72, c = r % 72;
        float v = (c < 64) ? dcn_w[o * 576 + c * 9 + k] : 0.f;
        ((unsigned short*)(ws + WTB_OFF))[t] = f2bf(v);
        return;
    }
    t -= 9 * 64 * 72;
    if (t < 9 * 32 * 64) {  // rwb[tap][o pad32][ci] bf16 = off_w[o][ci][tap]
        int tap = t >> 11, r = t & 2047, o = r >> 6, ci = r & 63;
        float v = (o < 27) ? off_w[o * 576 + ci * 9 + tap] : 0.f;
        ((unsigned short*)(ws + RWB_OFF))[t] = f2bf(v);
        return;
    }
    t -= 9 * 32 * 64;
    if (t < 8192) {  // wr1[ci*64+o] = w1[o*128+ci]
        int ci = t >> 6, o = t & 63;
        ws[WR1_OFF + t] = w1[o * 128 + ci];
        return;
    }
    t -= 8192;
    if (t < 16384) {  // wr2
        int ci = t >> 6, o = t & 63;
        ws[WR2_OFF + t] = w2[o * 256 + ci];
        return;
    }
    t -= 16384;
    if (t < 32768) {  // wr3
        int ci = t >> 6, o = t & 63;
        ws[WR3_OFF + t] = w3[o * 512 + ci];
        return;
    }
}

// conv1x1+BN for f1/f2/f3 in ONE kernel (thread = pixel, coalesced f loads, 64-reg acc,
// Cin split over 4 waves + padded-LDS tree reduce, coalesced NHWC store).
__global__ __launch_bounds__(256) void conv_all_kernel(
    const float* __restrict__ f1in, const float* __restrict__ f2in, const float* __restrict__ f3in,
    float* __restrict__ ws)
{
    __shared__ float R0[64 * 65];
    __shared__ float R1[64 * 65];
    __shared__ float SBl[128];

    int blk = blockIdx.x;
    const float* fin; const float* wr; const float* sbg; float* yout;
    int Cin, hw, tile;
    if (blk < 400)      { fin = f1in; wr = ws + WR1_OFF; sbg = ws + SB_OFF + 128; yout = ws + Y1_OFF; Cin = 128; hw = 6400; tile = blk; }
    else if (blk < 500) { fin = f2in; wr = ws + WR2_OFF; sbg = ws + SB_OFF + 256; yout = ws + Y2_OFF; Cin = 256; hw = 1600; tile = blk - 400; }
    else                { fin = f3in; wr = ws + WR3_OFF; sbg = ws + SB_OFF + 384; yout = ws + Y3_OFF; Cin = 512; hw = 400;  tile = blk - 500; }

    int tid  = threadIdx.x;
    int lane = tid & 63;
    int wv   = __builtin_amdgcn_readfirstlane(tid >> 6);

    if (tid < 128) SBl[tid] = sbg[tid];

    int P = tile * 64 + lane;
    int b = P / hw;
    int p = P - b * hw;

    int cq = Cin >> 2;
    const float* fb = fin + ((size_t)b * Cin + (size_t)wv * cq) * hw + p;
    const float* wq = wr + (wv * cq) * 64;

    float acc[64];
#pragma unroll
    for (int o = 0; o < 64; o++) acc[o] = 0.f;

    for (int c0 = 0; c0 < cq; c0 += 8) {
        float fv[8];
#pragma unroll
        for (int j = 0; j < 8; j++) fv[j] = fb[(size_t)(c0 + j) * hw];
#pragma unroll
        for (int j = 0; j < 8; j++) {
            const float* wrow = wq + (c0 + j) * 64;
#pragma unroll
            for (int o = 0; o < 64; o++) acc[o] = fmaf(fv[j], wrow[o], acc[o]);
        }
    }

    if (wv == 2) {
#pragma unroll
        for (int o = 0; o < 64; o++) R0[lane * 65 + o] = acc[o];
    }
    if (wv == 3) {
#pragma unroll
        for (int o = 0; o < 64; o++) R1[lane * 65 + o] = acc[o];
    }
    __syncthreads();
    if (wv == 0) {
#pragma unroll
        for (int o = 0; o < 64; o++) acc[o] += R0[lane * 65 + o];
    }
    if (wv == 1) {
#pragma unroll
        for (int o = 0; o < 64; o++) acc[o] += R1[lane * 65 + o];
    }
    __syncthreads();
    if (wv == 1) {
#pragma unroll
        for (int o = 0; o < 64; o++) R0[lane * 65 + o] = acc[o];
    }
    __syncthreads();
    if (wv == 0) {
#pragma unroll
        for (int o = 0; o < 64; o++) {
            float v = acc[o] + R0[lane * 65 + o];
            R1[lane * 65 + o] = fmaf(v, SBl[o], SBl[64 + o]);
        }
    }
    __syncthreads();

#pragma unroll
    for (int it = 0; it < 16; it++) {
        int idx = it * 256 + tid;
        int px = idx >> 6, o = idx & 63;
        yout[(size_t)(tile * 64 + px) * 64 + o] = R1[px * 65 + o];
    }
}

// fuse: phase-1 conv1x1(f0)+bn -> Ot (LDS), f0 loads 16-deep in flight;
// phase-2 upsample+relu -> x stored NHWC bf16.
__global__ __launch_bounds__(256) void fuse_kernel(const float* __restrict__ f0, float* __restrict__ ws)
{
    __shared__ float Ot[64 * 68];    // [px][ch pad 68] 17.4 KB

    int tid = threadIdx.x;
    int blk = blockIdx.x;
    int xcd = blk & 7, slot = blk >> 3;
    int b = xcd >> 1;
    int t = (xcd & 1) * 200 + slot;
    int p0 = t * 64;
    int lane = tid & 63;
    int cb = __builtin_amdgcn_readfirstlane(tid >> 6);
    int p = p0 + lane;
    const float* wr0 = ws + WR0_OFF + cb * 16;
    const float* sb  = ws + SB_OFF;  // bn0

    // phase 1: 16 f0 loads in flight per round
    {
        float acc[16];
#pragma unroll
        for (int i = 0; i < 16; i++) acc[i] = 0.f;

        const float* f0b = f0 + (size_t)b * 64 * HW_ + p;
        for (int ci0 = 0; ci0 < 64; ci0 += 16) {
            float fv[16];
#pragma unroll
            for (int j = 0; j < 16; j++) fv[j] = f0b[(size_t)(ci0 + j) * HW_];
#pragma unroll
            for (int j = 0; j < 16; j++) {
                const float* wrow = wr0 + (ci0 + j) * 64;
#pragma unroll
                for (int i = 0; i < 16; i++) acc[i] = fmaf(fv[j], wrow[i], acc[i]);
            }
        }
        float* orow = Ot + lane * 68 + cb * 16;
#pragma unroll
        for (int i = 0; i < 16; i++) {
            int o = cb * 16 + i;
            orow[i] = fmaf(acc[i], sb[o], sb[64 + o]);
        }
    }
    __syncthreads();

    // phase 2: upsample + relu + bf16 pack + store
    {
        int chunk = lane & 15, pxo = lane >> 4;
        unsigned short* xb = (unsigned short*)(ws + X_OFF) + ((size_t)b * HW_ + p0) * 64;
#pragma unroll
        for (int r = 0; r < 4; r++) {
            int gpx = cb * 16 + r * 4 + pxo;
            int gp = p0 + gpx;
            int h = gp / W_, w = gp % W_;

            float fy1 = h * (79.f / 159.f); int i1 = (int)fy1; if (i1 > 78) i1 = 78; float ty1 = fy1 - i1;
            float fx1 = w * (79.f / 159.f); int j1 = (int)fx1; if (j1 > 78) j1 = 78; float tx1 = fx1 - j1;
            const float* y1 = ws + Y1_OFF + ((size_t)b * 6400 + (size_t)(i1 * 80 + j1)) * 64 + chunk * 4;
            float fy2 = h * (39.f / 159.f); int i2 = (int)fy2; if (i2 > 38) i2 = 38; float ty2 = fy2 - i2;
            float fx2 = w * (39.f / 159.f); int j2 = (int)fx2; if (j2 > 38) j2 = 38; float tx2 = fx2 - j2;
            const float* y2 = ws + Y2_OFF + ((size_t)b * 1600 + (size_t)(i2 * 40 + j2)) * 64 + chunk * 4;
            float fy3 = h * (19.f / 159.f); int i3 = (int)fy3; if (i3 > 18) i3 = 18; float ty3 = fy3 - i3;
            float fx3 = w * (19.f / 159.f); int j3 = (int)fx3; if (j3 > 18) j3 = 18; float tx3 = fx3 - j3;
            const float* y3 = ws + Y3_OFF + ((size_t)b * 400 + (size_t)(i3 * 20 + j3)) * 64 + chunk * 4;

            f32x4 A[12];
            A[0]  = *(const f32x4*)(y1);
            A[1]  = *(const f32x4*)(y1 + 64);
            A[2]  = *(const f32x4*)(y1 + 80 * 64);
            A[3]  = *(const f32x4*)(y1 + 81 * 64);
            A[4]  = *(const f32x4*)(y2);
            A[5]  = *(const f32x4*)(y2 + 64);
            A[6]  = *(const f32x4*)(y2 + 40 * 64);
            A[7]  = *(const f32x4*)(y2 + 41 * 64);
            A[8]  = *(const f32x4*)(y3);
            A[9]  = *(const f32x4*)(y3 + 64);
            A[10] = *(const f32x4*)(y3 + 20 * 64);
            A[11] = *(const f32x4*)(y3 + 21 * 64);

            f32x4 v = *(const f32x4*)(Ot + gpx * 68 + chunk * 4);

            float w00, w01, w10, w11;
            w00 = (1.f - ty1) * (1.f - tx1); w01 = (1.f - ty1) * tx1; w10 = ty1 * (1.f - tx1); w11 = ty1 * tx1;
#pragma unroll
            for (int j = 0; j < 4; j++)
                v[j] += A[0][j] * w00 + A[1][j] * w01 + A[2][j] * w10 + A[3][j] * w11;
            w00 = (1.f - ty2) * (1.f - tx2); w01 = (1.f - ty2) * tx2; w10 = ty2 * (1.f - tx2); w11 = ty2 * tx2;
#pragma unroll
            for (int j = 0; j < 4; j++)
                v[j] += A[4][j] * w00 + A[5][j] * w01 + A[6][j] * w10 + A[7][j] * w11;
            w00 = (1.f - ty3) * (1.f - tx3); w01 = (1.f - ty3) * tx3; w10 = ty3 * (1.f - tx3); w11 = ty3 * tx3;
#pragma unroll
            for (int j = 0; j < 4; j++)
                v[j] += A[8][j] * w00 + A[9][j] * w01 + A[10][j] * w10 + A[11][j] * w11;

#pragma unroll
            for (int j = 0; j < 4; j++) v[j] = fmaxf(v[j], 0.f);
            unsigned int lo = ((unsigned int)f2bf(v[1]) << 16) | f2bf(v[0]);
            unsigned int hi = ((unsigned int)f2bf(v[3]) << 16) | f2bf(v[2]);
            *(u32x2*)(xb + (size_t)gpx * 64 + chunk * 4) = (u32x2){lo, hi};
        }
    }
}

// FUSED offconv + dcn, x read as bf16 NHWC. (256,6) = r6's best config.
// DELTA vs r6 (the only change this round): phase-2 gathers issue all 16 corner loads
// in one round (was 2 serial half-rounds of 8) -> one latency window per tap instead
// of two. bf16 g[4][4] = 32 VGPR, fits the 85-VGPR cap at 6 waves/SIMD.
__global__ __launch_bounds__(256, 6) void dcn_fused_kernel(const float* __restrict__ off_b,
                                                           float* __restrict__ ws, float* __restrict__ out)
{
    __shared__ __align__(16) unsigned short A_lds[2][64 * 72];  // tap-pair; reused as C overlays
    __shared__ float OMs[64 * 27];                              // (sy,sx,mk)*9 per px

    int tid = threadIdx.x;
    int blk = blockIdx.x;
    int xcd = blk & 7, slot = blk >> 3;
    int b = xcd >> 1;
    int t = (xcd & 1) * 200 + slot;
    int p0 = t * 64;
    int lane = tid & 63, cb = tid >> 6;
    int px = lane;
    int p = p0 + px;
    int h = p / W_, w = p % W_;
    int mrow = lane & 15, quad = lane >> 4;
    int chunk = lane & 15, pxo = lane >> 4;   // gather mapping

    const unsigned short* rwb = (const unsigned short*)(ws + RWB_OFF);
    const unsigned short* wtb = (const unsigned short*)(ws + WTB_OFF);
    const unsigned short* xbh = (const unsigned short*)(ws + X_OFF) + (size_t)b * HW_ * 64;
    const float* sb = ws + SB_OFF + 4 * 128;  // final bn

    // ============ phase 1: offset/mask 3x3 conv (GEMM N=27 pad 32) ============
    {
        f32x4 acc2[2];
        acc2[0] = (f32x4){0.f, 0.f, 0.f, 0.f};
        acc2[1] = (f32x4){0.f, 0.f, 0.f, 0.f};

        for (int kk = 0; kk < 9; kk += 2) {
#pragma unroll
            for (int u = 0; u < 2; u++) {
                int tap = kk + u;
                if (tap > 8) break;
                int dy = tap / 3 - 1, dx = tap % 3 - 1;
                int delta = dy * W_ + dx;
                int  pss[4];
                bool vlds[4];
#pragma unroll
                for (int r = 0; r < 4; r++) {
                    int gpx = cb * 16 + r * 4 + pxo;
                    int gp = p0 + gpx;
                    int gh = gp / W_, gw = gp % W_;
                    int yy = gh + dy, xx = gw + dx;
                    vlds[r] = (yy >= 0) && (yy < H_) && (xx >= 0) && (xx < W_);
                    int ps = gp + delta;
                    pss[r] = min(max(ps, 0), HW_ - 1);
                }
                u32x2 g[4];
#pragma unroll
                for (int r = 0; r < 4; r++)
                    g[r] = *(const u32x2*)(xbh + (size_t)pss[r] * 64 + chunk * 4);
#pragma unroll
                for (int r = 0; r < 4; r++) {
                    int gpx = cb * 16 + r * 4 + pxo;
                    u32x2 gv;
                    gv.x = vlds[r] ? g[r].x : 0u;
                    gv.y = vlds[r] ? g[r].y : 0u;
                    *(u32x2*)(A_lds[u] + gpx * 72 + chunk * 4) = gv;
                }
            }

#pragma unroll
            for (int u = 0; u < 2; u++) {
                int tap = kk + u;
                if (tap > 8) break;
                const unsigned short* Ab = A_lds[u] + (cb * 16 + mrow) * 72;
#pragma unroll
                for (int ks = 0; ks < 2; ks++) {
                    bf16x8 af = *(const bf16x8*)(Ab + ks * 32 + quad * 8);
#pragma unroll
                    for (int nt = 0; nt < 2; nt++) {
                        bf16x8 bf_ = *(const bf16x8*)(rwb + tap * 2048 + (nt * 16 + mrow) * 64 + ks * 32 + quad * 8);
                        acc2[nt] = __builtin_amdgcn_mfma_f32_16x16x32_bf16(af, bf_, acc2[nt], 0, 0, 0);
                    }
                }
            }
        }

        __syncthreads();
        float* Cl = (float*)A_lds;  // [64 px][28]
#pragma unroll
        for (int nt = 0; nt < 2; nt++) {
            int o = nt * 16 + mrow;
            if (o < 27) {
                int pr = cb * 16 + quad * 4;
#pragma unroll
                for (int r = 0; r < 4; r++) Cl[(pr + r) * 28 + o] = acc2[nt][r];
            }
        }
        __syncthreads();

        for (int k = cb; k < 9; k += 4) {
            float ady = Cl[px * 28 + 2 * k]     + off_b[2 * k];
            float adx = Cl[px * 28 + 2 * k + 1] + off_b[2 * k + 1];
            float am  = Cl[px * 28 + 18 + k]    + off_b[18 + k];
            float sy = (float)(h + k / 3 - 1) + ady;
            float sx = (float)(w + k % 3 - 1) + adx;
            float mk = 1.f / (1.f + __expf(-am));
            OMs[px * 27 + 3 * k]     = sy;
            OMs[px * 27 + 3 * k + 1] = sx;
            OMs[px * 27 + 3 * k + 2] = mk;
        }
        __syncthreads();
    }

    // ============ phase 2: modulated deformable conv (GEMM N=64) ============
    f32x4 acc[4];
#pragma unroll
    for (int nt = 0; nt < 4; nt++) acc[nt] = (f32x4){0.f, 0.f, 0.f, 0.f};

    for (int kk = 0; kk < 9; kk += 2) {
#pragma unroll
        for (int u = 0; u < 2; u++) {
            int k = kk + u;
            if (k > 8) break;
            // all 16 corner loads in flight (one latency window per tap)
            float wvs[4][4];
            u32x2 g[4][4];
            {
                int idxs[4][4];
#pragma unroll
                for (int r = 0; r < 4; r++) {
                    int gpx = cb * 16 + r * 4 + pxo;
                    float sy = OMs[gpx * 27 + 3 * k];
                    float sx = OMs[gpx * 27 + 3 * k + 1];
                    float mk = OMs[gpx * 27 + 3 * k + 2];
                    float y0f = floorf(sy), x0f = floorf(sx);
                    int y0 = (int)y0f, x0 = (int)x0f;
                    float ty = sy - y0f, tx = sx - x0f;
#pragma unroll
                    for (int cr = 0; cr < 4; cr++) {
                        int dy = cr >> 1, dx = cr & 1;
                        int yy = y0 + dy, xx = x0 + dx;
                        float wy = dy ? ty : 1.f - ty;
                        float wx = dx ? tx : 1.f - tx;
                        bool vld = (yy >= 0) && (yy < H_) && (xx >= 0) && (xx < W_);
                        int yc = min(max(yy, 0), H_ - 1);
                        int xc = min(max(xx, 0), W_ - 1);
                        idxs[r][cr] = yc * W_ + xc;
                        wvs[r][cr]  = vld ? wy * wx * mk : 0.f;
                    }
                }
#pragma unroll
                for (int r = 0; r < 4; r++)
#pragma unroll
                    for (int cr = 0; cr < 4; cr++)
                        g[r][cr] = *(const u32x2*)(xbh + (size_t)idxs[r][cr] * 64 + chunk * 4);
            }
#pragma unroll
            for (int r = 0; r < 4; r++) {
                int gpx = cb * 16 + r * 4 + pxo;
                f32x4 v = (f32x4){0.f, 0.f, 0.f, 0.f};
#pragma unroll
                for (int cr = 0; cr < 4; cr++) {
                    float wv = wvs[r][cr];
                    float e0 = __uint_as_float(g[r][cr].x << 16);
                    float e1 = __uint_as_float(g[r][cr].x & 0xffff0000u);
                    float e2 = __uint_as_float(g[r][cr].y << 16);
                    float e3 = __uint_as_float(g[r][cr].y & 0xffff0000u);
                    v[0] = fmaf(e0, wv, v[0]);
                    v[1] = fmaf(e1, wv, v[1]);
                    v[2] = fmaf(e2, wv, v[2]);
                    v[3] = fmaf(e3, wv, v[3]);
                }
                unsigned int lo = ((unsigned int)f2bf(v[1]) << 16) | f2bf(v[0]);
                unsigned int hi = ((unsigned int)f2bf(v[3]) << 16) | f2bf(v[2]);
                *(u32x2*)(A_lds[u] + gpx * 72 + chunk * 4) = (u32x2){lo, hi};
            }
        }

#pragma unroll
        for (int u = 0; u < 2; u++) {
            int k = kk + u;
            if (k > 8) break;
            const unsigned short* Ab = A_lds[u] + (cb * 16 + mrow) * 72;
#pragma unroll
            for (int ks = 0; ks < 2; ks++) {
                bf16x8 af = *(const bf16x8*)(Ab + ks * 32 + quad * 8);
#pragma unroll
                for (int nt = 0; nt < 4; nt++) {
                    bf16x8 bf_ = *(const bf16x8*)(wtb + k * 4608 + (nt * 16 + mrow) * 72 + ks * 32 + quad * 8);
                    acc[nt] = __builtin_amdgcn_mfma_f32_16x16x32_bf16(af, bf_, acc[nt], 0, 0, 0);
                }
            }
        }
    }

    // epilogue: C frag -> LDS [o][px pad65] -> NCHW store
    __syncthreads();
    float* C_lds = (float*)A_lds;
#pragma unroll
    for (int nt = 0; nt < 4; nt++) {
        int o = nt * 16 + mrow;
        int pxb = cb * 16 + quad * 4;
#pragma unroll
        for (int r = 0; r < 4; r++) C_lds[o * 65 + pxb + r] = acc[nt][r];
    }
    __syncthreads();
#pragma unroll
    for (int i = 0; i < 16; i++) {
        int o = cb * 16 + i;
        float v = C_lds[o * 65 + lane];
        v = fmaf(v, sb[o], sb[64 + o]);
        out[((size_t)b * 64 + o) * HW_ + p0 + lane] = fmaxf(v, 0.f);
    }
}

extern "C" void kernel_launch(void* const* d_in, const int* in_sizes, int n_in,
                              void* d_out, int out_size, void* d_ws, size_t ws_size,
                              hipStream_t stream)
{
    const float* f0 = (const float*)d_in[0];
    const float* f1 = (const float*)d_in[1];
    const float* f2 = (const float*)d_in[2];
    const float* f3 = (const float*)d_in[3];
    const float* w0 = (const float*)d_in[4];
    const float* g0 = (const float*)d_in[5];
    const float* b0 = (const float*)d_in[6];
    const float* m0 = (const float*)d_in[7];
    const float* v0 = (const float*)d_in[8];
    const float* w1 = (const float*)d_in[9];
    const float* g1 = (const float*)d_in[10];
    const float* b1 = (const float*)d_in[11];
    const float* m1 = (const float*)d_in[12];
    const float* v1 = (const float*)d_in[13];
    const float* w2 = (const float*)d_in[14];
    const float* g2 = (const float*)d_in[15];
    const float* b2 = (const float*)d_in[16];
    const float* m2 = (const float*)d_in[17];
    const float* v2 = (const float*)d_in[18];
    const float* w3 = (const float*)d_in[19];
    const float* g3 = (const float*)d_in[20];
    const float* b3 = (const float*)d_in[21];
    const float* m3 = (const float*)d_in[22];
    const float* v3 = (const float*)d_in[23];
    const float* off_w = (const float*)d_in[24];
    const float* off_b = (const float*)d_in[25];
    const float* dcn_w = (const float*)d_in[26];
    const float* gf = (const float*)d_in[27];
    const float* bf = (const float*)d_in[28];
    const float* mf = (const float*)d_in[29];
    const float* vf = (const float*)d_in[30];

    float* ws  = (float*)d_ws;
    float* out = (float*)d_out;

    prep_kernel<<<dim3(476), dim3(256), 0, stream>>>(
        g0, b0, m0, v0, g1, b1, m1, v1, g2, b2, m2, v2, g3, b3, m3, v3,
        gf, bf, mf, vf, w0, w1, w2, w3, dcn_w, off_w, ws);

    conv_all_kernel<<<dim3(525), dim3(256), 0, stream>>>(f1, f2, f3, ws);

    fuse_kernel<<<dim3(1600), dim3(256), 0, stream>>>(f0, ws);

    dcn_fused_kernel<<<dim3(1600), dim3(256), 0, stream>>>(off_b, ws, out);
}

// Round 10
// 291.855 us; speedup vs baseline: 1.3199x; 1.1085x over previous
//
#include <hip/hip_runtime.h>
#include <math.h>

#define EPSB 1e-5f

constexpr int B_ = 4;
constexpr int C_ = 64;
constexpr int H_ = 160;
constexpr int W_ = 160;
constexpr int HW_ = H_ * W_;

// workspace layout (float offsets)
constexpr size_t X_OFF   = 0;                                    // x NHWC bf16: [b][p][64] (half the region)
constexpr size_t Y1_OFF  = X_OFF  + (size_t)B_ * HW_ * 64;       // y1 NHWC @80x80 (fp32)
constexpr size_t Y2_OFF  = Y1_OFF + (size_t)B_ * 6400 * 64;      // y2 NHWC @40x40
constexpr size_t Y3_OFF  = Y2_OFF + (size_t)B_ * 1600 * 64;      // y3 NHWC @20x20
constexpr size_t OM_OFF  = Y3_OFF + (size_t)B_ * 400 * 64;       // (unused)
constexpr size_t WR0_OFF = OM_OFF + (size_t)B_ * HW_ * 27;       // w0 fp32 [ci][o]: 4096
constexpr size_t WTB_OFF = WR0_OFF + 4096;                       // dcn_w bf16 [k][o][c pad72]: 41472 ush
constexpr size_t RWB_OFF = WTB_OFF + (9 * 64 * 72) / 2;          // off_w bf16 [tap][o pad32][ci]: 18432 ush
constexpr size_t SB_OFF  = RWB_OFF + (9 * 32 * 64) / 2;          // 5 BNs x (scale[64], bias[64])
// transposed conv1x1 weights OVERLAID at head of X region (die before fuse writes x).
constexpr size_t WR1_OFF = X_OFF + 0;       // w1 fp32 [ci][o]
constexpr size_t WR2_OFF = X_OFF + 8192;    // w2 fp32 [ci][o]
constexpr size_t WR3_OFF = X_OFF + 24576;   // w3 fp32 [ci][o]

typedef short bf16x8 __attribute__((ext_vector_type(8)));
typedef float f32x4 __attribute__((ext_vector_type(4)));
typedef unsigned int u32x2 __attribute__((ext_vector_type(2)));

static __device__ __forceinline__ unsigned short f2bf(float f) {
    unsigned int u = __float_as_uint(f);
    u += 0x7fff + ((u >> 16) & 1);   // RNE
    return (unsigned short)(u >> 16);
}

__global__ __launch_bounds__(256) void prep_kernel(
    const float* __restrict__ g0, const float* __restrict__ b0, const float* __restrict__ m0, const float* __restrict__ v0,
    const float* __restrict__ g1, const float* __restrict__ b1, const float* __restrict__ m1, const float* __restrict__ v1,
    const float* __restrict__ g2, const float* __restrict__ b2, const float* __restrict__ m2, const float* __restrict__ v2,
    const float* __restrict__ g3, const float* __restrict__ b3, const float* __restrict__ m3, const float* __restrict__ v3,
    const float* __restrict__ gf, const float* __restrict__ bf, const float* __restrict__ mf, const float* __restrict__ vf,
    const float* __restrict__ w0, const float* __restrict__ w1, const float* __restrict__ w2, const float* __restrict__ w3,
    const float* __restrict__ dcn_w, const float* __restrict__ off_w,
    float* __restrict__ ws)
{
    int tid = blockIdx.x * 256 + threadIdx.x;
    if (tid < 320) {  // BN scale/bias fold
        int j = tid >> 6, c = tid & 63;
        const float *g, *b, *m, *v;
        switch (j) {
            case 0: g = g0; b = b0; m = m0; v = v0; break;
            case 1: g = g1; b = b1; m = m1; v = v1; break;
            case 2: g = g2; b = b2; m = m2; v = v2; break;
            case 3: g = g3; b = b3; m = m3; v = v3; break;
            default: g = gf; b = bf; m = mf; v = vf; break;
        }
        float sc = g[c] * rsqrtf(v[c] + EPSB);
        ws[SB_OFF + j * 128 + c]      = sc;
        ws[SB_OFF + j * 128 + 64 + c] = b[c] - m[c] * sc;
        return;
    }
    int t = tid - 320;
    if (t < 4096) {  // wr0[ci*64+o] = w0[o*64+ci]
        int ci = t >> 6, o = t & 63;
        ws[WR0_OFF + t] = w0[o * 64 + ci];
        return;
    }
    t -= 4096;
    if (t < 9 * 64 * 72) {  // wtb[k][o][c pad72] bf16 = dcn_w[o][c][k]
        int k = t / 4608, r = t % 4608, o = r / 72, c = r % 72;
        float v = (c < 64) ? dcn_w[o * 576 + c * 9 + k] : 0.f;
        ((unsigned short*)(ws + WTB_OFF))[t] = f2bf(v);
        return;
    }
    t -= 9 * 64 * 72;
    if (t < 9 * 32 * 64) {  // rwb[tap][o pad32][ci] bf16 = off_w[o][ci][tap]
        int tap = t >> 11, r = t & 2047, o = r >> 6, ci = r & 63;
        float v = (o < 27) ? off_w[o * 576 + ci * 9 + tap] : 0.f;
        ((unsigned short*)(ws + RWB_OFF))[t] = f2bf(v);
        return;
    }
    t -= 9 * 32 * 64;
    if (t < 8192) {  // wr1[ci*64+o] = w1[o*128+ci]
        int ci = t >> 6, o = t & 63;
        ws[WR1_OFF + t] = w1[o * 128 + ci];
        return;
    }
    t -= 8192;
    if (t < 16384) {  // wr2
        int ci = t >> 6, o = t & 63;
        ws[WR2_OFF + t] = w2[o * 256 + ci];
        return;
    }
    t -= 16384;
    if (t < 32768) {  // wr3
        int ci = t >> 6, o = t & 63;
        ws[WR3_OFF + t] = w3[o * 512 + ci];
        return;
    }
}

// conv1x1+BN for f1/f2/f3 in ONE kernel (thread = pixel, coalesced f loads, 64-reg acc,
// Cin split over 4 waves + padded-LDS tree reduce, coalesced NHWC store).
// DELTA this round: f loads 16-deep in flight (was 8) — conv_all runs at only 2 blocks/CU
// (525-block grid) so HBM latency must be hidden by ILP, not TLP. No launch-bound min-wave
// -> 256-VGPR budget, acc[64]+fv[16] fits with no spill.
__global__ __launch_bounds__(256) void conv_all_kernel(
    const float* __restrict__ f1in, const float* __restrict__ f2in, const float* __restrict__ f3in,
    float* __restrict__ ws)
{
    __shared__ float R0[64 * 65];
    __shared__ float R1[64 * 65];
    __shared__ float SBl[128];

    int blk = blockIdx.x;
    const float* fin; const float* wr; const float* sbg; float* yout;
    int Cin, hw, tile;
    if (blk < 400)      { fin = f1in; wr = ws + WR1_OFF; sbg = ws + SB_OFF + 128; yout = ws + Y1_OFF; Cin = 128; hw = 6400; tile = blk; }
    else if (blk < 500) { fin = f2in; wr = ws + WR2_OFF; sbg = ws + SB_OFF + 256; yout = ws + Y2_OFF; Cin = 256; hw = 1600; tile = blk - 400; }
    else                { fin = f3in; wr = ws + WR3_OFF; sbg = ws + SB_OFF + 384; yout = ws + Y3_OFF; Cin = 512; hw = 400;  tile = blk - 500; }

    int tid  = threadIdx.x;
    int lane = tid & 63;
    int wv   = __builtin_amdgcn_readfirstlane(tid >> 6);

    if (tid < 128) SBl[tid] = sbg[tid];

    int P = tile * 64 + lane;
    int b = P / hw;
    int p = P - b * hw;

    int cq = Cin >> 2;
    const float* fb = fin + ((size_t)b * Cin + (size_t)wv * cq) * hw + p;
    const float* wq = wr + (wv * cq) * 64;

    float acc[64];
#pragma unroll
    for (int o = 0; o < 64; o++) acc[o] = 0.f;

    for (int c0 = 0; c0 < cq; c0 += 16) {
        float fv[16];
#pragma unroll
        for (int j = 0; j < 16; j++) fv[j] = fb[(size_t)(c0 + j) * hw];
#pragma unroll
        for (int j = 0; j < 16; j++) {
            const float* wrow = wq + (c0 + j) * 64;
#pragma unroll
            for (int o = 0; o < 64; o++) acc[o] = fmaf(fv[j], wrow[o], acc[o]);
        }
    }

    if (wv == 2) {
#pragma unroll
        for (int o = 0; o < 64; o++) R0[lane * 65 + o] = acc[o];
    }
    if (wv == 3) {
#pragma unroll
        for (int o = 0; o < 64; o++) R1[lane * 65 + o] = acc[o];
    }
    __syncthreads();
    if (wv == 0) {
#pragma unroll
        for (int o = 0; o < 64; o++) acc[o] += R0[lane * 65 + o];
    }
    if (wv == 1) {
#pragma unroll
        for (int o = 0; o < 64; o++) acc[o] += R1[lane * 65 + o];
    }
    __syncthreads();
    if (wv == 1) {
#pragma unroll
        for (int o = 0; o < 64; o++) R0[lane * 65 + o] = acc[o];
    }
    __syncthreads();
    if (wv == 0) {
#pragma unroll
        for (int o = 0; o < 64; o++) {
            float v = acc[o] + R0[lane * 65 + o];
            R1[lane * 65 + o] = fmaf(v, SBl[o], SBl[64 + o]);
        }
    }
    __syncthreads();

#pragma unroll
    for (int it = 0; it < 16; it++) {
        int idx = it * 256 + tid;
        int px = idx >> 6, o = idx & 63;
        yout[(size_t)(tile * 64 + px) * 64 + o] = R1[px * 65 + o];
    }
}

// fuse: phase-1 conv1x1(f0)+bn -> Ot (LDS), f0 loads 16-deep in flight;
// phase-2 upsample+relu -> x stored NHWC bf16.
__global__ __launch_bounds__(256) void fuse_kernel(const float* __restrict__ f0, float* __restrict__ ws)
{
    __shared__ float Ot[64 * 68];    // [px][ch pad 68] 17.4 KB

    int tid = threadIdx.x;
    int blk = blockIdx.x;
    int xcd = blk & 7, slot = blk >> 3;
    int b = xcd >> 1;
    int t = (xcd & 1) * 200 + slot;
    int p0 = t * 64;
    int lane = tid & 63;
    int cb = __builtin_amdgcn_readfirstlane(tid >> 6);
    int p = p0 + lane;
    const float* wr0 = ws + WR0_OFF + cb * 16;
    const float* sb  = ws + SB_OFF;  // bn0

    // phase 1: 16 f0 loads in flight per round
    {
        float acc[16];
#pragma unroll
        for (int i = 0; i < 16; i++) acc[i] = 0.f;

        const float* f0b = f0 + (size_t)b * 64 * HW_ + p;
        for (int ci0 = 0; ci0 < 64; ci0 += 16) {
            float fv[16];
#pragma unroll
            for (int j = 0; j < 16; j++) fv[j] = f0b[(size_t)(ci0 + j) * HW_];
#pragma unroll
            for (int j = 0; j < 16; j++) {
                const float* wrow = wr0 + (ci0 + j) * 64;
#pragma unroll
                for (int i = 0; i < 16; i++) acc[i] = fmaf(fv[j], wrow[i], acc[i]);
            }
        }
        float* orow = Ot + lane * 68 + cb * 16;
#pragma unroll
        for (int i = 0; i < 16; i++) {
            int o = cb * 16 + i;
            orow[i] = fmaf(acc[i], sb[o], sb[64 + o]);
        }
    }
    __syncthreads();

    // phase 2: upsample + relu + bf16 pack + store
    {
        int chunk = lane & 15, pxo = lane >> 4;
        unsigned short* xb = (unsigned short*)(ws + X_OFF) + ((size_t)b * HW_ + p0) * 64;
#pragma unroll
        for (int r = 0; r < 4; r++) {
            int gpx = cb * 16 + r * 4 + pxo;
            int gp = p0 + gpx;
            int h = gp / W_, w = gp % W_;

            float fy1 = h * (79.f / 159.f); int i1 = (int)fy1; if (i1 > 78) i1 = 78; float ty1 = fy1 - i1;
            float fx1 = w * (79.f / 159.f); int j1 = (int)fx1; if (j1 > 78) j1 = 78; float tx1 = fx1 - j1;
            const float* y1 = ws + Y1_OFF + ((size_t)b * 6400 + (size_t)(i1 * 80 + j1)) * 64 + chunk * 4;
            float fy2 = h * (39.f / 159.f); int i2 = (int)fy2; if (i2 > 38) i2 = 38; float ty2 = fy2 - i2;
            float fx2 = w * (39.f / 159.f); int j2 = (int)fx2; if (j2 > 38) j2 = 38; float tx2 = fx2 - j2;
            const float* y2 = ws + Y2_OFF + ((size_t)b * 1600 + (size_t)(i2 * 40 + j2)) * 64 + chunk * 4;
            float fy3 = h * (19.f / 159.f); int i3 = (int)fy3; if (i3 > 18) i3 = 18; float ty3 = fy3 - i3;
            float fx3 = w * (19.f / 159.f); int j3 = (int)fx3; if (j3 > 18) j3 = 18; float tx3 = fx3 - j3;
            const float* y3 = ws + Y3_OFF + ((size_t)b * 400 + (size_t)(i3 * 20 + j3)) * 64 + chunk * 4;

            f32x4 A[12];
            A[0]  = *(const f32x4*)(y1);
            A[1]  = *(const f32x4*)(y1 + 64);
            A[2]  = *(const f32x4*)(y1 + 80 * 64);
            A[3]  = *(const f32x4*)(y1 + 81 * 64);
            A[4]  = *(const f32x4*)(y2);
            A[5]  = *(const f32x4*)(y2 + 64);
            A[6]  = *(const f32x4*)(y2 + 40 * 64);
            A[7]  = *(const f32x4*)(y2 + 41 * 64);
            A[8]  = *(const f32x4*)(y3);
            A[9]  = *(const f32x4*)(y3 + 64);
            A[10] = *(const f32x4*)(y3 + 20 * 64);
            A[11] = *(const f32x4*)(y3 + 21 * 64);

            f32x4 v = *(const f32x4*)(Ot + gpx * 68 + chunk * 4);

            float w00, w01, w10, w11;
            w00 = (1.f - ty1) * (1.f - tx1); w01 = (1.f - ty1) * tx1; w10 = ty1 * (1.f - tx1); w11 = ty1 * tx1;
#pragma unroll
            for (int j = 0; j < 4; j++)
                v[j] += A[0][j] * w00 + A[1][j] * w01 + A[2][j] * w10 + A[3][j] * w11;
            w00 = (1.f - ty2) * (1.f - tx2); w01 = (1.f - ty2) * tx2; w10 = ty2 * (1.f - tx2); w11 = ty2 * tx2;
#pragma unroll
            for (int j = 0; j < 4; j++)
                v[j] += A[4][j] * w00 + A[5][j] * w01 + A[6][j] * w10 + A[7][j] * w11;
            w00 = (1.f - ty3) * (1.f - tx3); w01 = (1.f - ty3) * tx3; w10 = ty3 * (1.f - tx3); w11 = ty3 * tx3;
#pragma unroll
            for (int j = 0; j < 4; j++)
                v[j] += A[8][j] * w00 + A[9][j] * w01 + A[10][j] * w10 + A[11][j] * w11;

#pragma unroll
            for (int j = 0; j < 4; j++) v[j] = fmaxf(v[j], 0.f);
            unsigned int lo = ((unsigned int)f2bf(v[1]) << 16) | f2bf(v[0]);
            unsigned int hi = ((unsigned int)f2bf(v[3]) << 16) | f2bf(v[2]);
            *(u32x2*)(xb + (size_t)gpx * 64 + chunk * 4) = (u32x2){lo, hi};
        }
    }
}

// FUSED offconv + dcn, x read as bf16 NHWC — EXACT r6 revert (best measured: 102 µs).
// (256,6); phase-2 gathers in two half-rounds of 8 (the 85-VGPR-cap pressure ceiling;
// 16-in-flight spills -> 103MB scratch WRITE, r9).
__global__ __launch_bounds__(256, 6) void dcn_fused_kernel(const float* __restrict__ off_b,
                                                           float* __restrict__ ws, float* __restrict__ out)
{
    __shared__ __align__(16) unsigned short A_lds[2][64 * 72];  // tap-pair; reused as C overlays
    __shared__ float OMs[64 * 27];                              // (sy,sx,mk)*9 per px

    int tid = threadIdx.x;
    int blk = blockIdx.x;
    int xcd = blk & 7, slot = blk >> 3;
    int b = xcd >> 1;
    int t = (xcd & 1) * 200 + slot;
    int p0 = t * 64;
    int lane = tid & 63, cb = tid >> 6;
    int px = lane;
    int p = p0 + px;
    int h = p / W_, w = p % W_;
    int mrow = lane & 15, quad = lane >> 4;
    int chunk = lane & 15, pxo = lane >> 4;   // gather mapping

    const unsigned short* rwb = (const unsigned short*)(ws + RWB_OFF);
    const unsigned short* wtb = (const unsigned short*)(ws + WTB_OFF);
    const unsigned short* xbh = (const unsigned short*)(ws + X_OFF) + (size_t)b * HW_ * 64;
    const float* sb = ws + SB_OFF + 4 * 128;  // final bn

    // ============ phase 1: offset/mask 3x3 conv (GEMM N=27 pad 32) ============
    {
        f32x4 acc2[2];
        acc2[0] = (f32x4){0.f, 0.f, 0.f, 0.f};
        acc2[1] = (f32x4){0.f, 0.f, 0.f, 0.f};

        for (int kk = 0; kk < 9; kk += 2) {
#pragma unroll
            for (int u = 0; u < 2; u++) {
                int tap = kk + u;
                if (tap > 8) break;
                int dy = tap / 3 - 1, dx = tap % 3 - 1;
                int delta = dy * W_ + dx;
                int  pss[4];
                bool vlds[4];
#pragma unroll
                for (int r = 0; r < 4; r++) {
                    int gpx = cb * 16 + r * 4 + pxo;
                    int gp = p0 + gpx;
                    int gh = gp / W_, gw = gp % W_;
                    int yy = gh + dy, xx = gw + dx;
                    vlds[r] = (yy >= 0) && (yy < H_) && (xx >= 0) && (xx < W_);
                    int ps = gp + delta;
                    pss[r] = min(max(ps, 0), HW_ - 1);
                }
                u32x2 g[4];
#pragma unroll
                for (int r = 0; r < 4; r++)
                    g[r] = *(const u32x2*)(xbh + (size_t)pss[r] * 64 + chunk * 4);
#pragma unroll
                for (int r = 0; r < 4; r++) {
                    int gpx = cb * 16 + r * 4 + pxo;
                    u32x2 gv;
                    gv.x = vlds[r] ? g[r].x : 0u;
                    gv.y = vlds[r] ? g[r].y : 0u;
                    *(u32x2*)(A_lds[u] + gpx * 72 + chunk * 4) = gv;
                }
            }

#pragma unroll
            for (int u = 0; u < 2; u++) {
                int tap = kk + u;
                if (tap > 8) break;
                const unsigned short* Ab = A_lds[u] + (cb * 16 + mrow) * 72;
#pragma unroll
                for (int ks = 0; ks < 2; ks++) {
                    bf16x8 af = *(const bf16x8*)(Ab + ks * 32 + quad * 8);
#pragma unroll
                    for (int nt = 0; nt < 2; nt++) {
                        bf16x8 bf_ = *(const bf16x8*)(rwb + tap * 2048 + (nt * 16 + mrow) * 64 + ks * 32 + quad * 8);
                        acc2[nt] = __builtin_amdgcn_mfma_f32_16x16x32_bf16(af, bf_, acc2[nt], 0, 0, 0);
                    }
                }
            }
        }

        __syncthreads();
        float* Cl = (float*)A_lds;  // [64 px][28]
#pragma unroll
        for (int nt = 0; nt < 2; nt++) {
            int o = nt * 16 + mrow;
            if (o < 27) {
                int pr = cb * 16 + quad * 4;
#pragma unroll
                for (int r = 0; r < 4; r++) Cl[(pr + r) * 28 + o] = acc2[nt][r];
            }
        }
        __syncthreads();

        for (int k = cb; k < 9; k += 4) {
            float ady = Cl[px * 28 + 2 * k]     + off_b[2 * k];
            float adx = Cl[px * 28 + 2 * k + 1] + off_b[2 * k + 1];
            float am  = Cl[px * 28 + 18 + k]    + off_b[18 + k];
            float sy = (float)(h + k / 3 - 1) + ady;
            float sx = (float)(w + k % 3 - 1) + adx;
            float mk = 1.f / (1.f + __expf(-am));
            OMs[px * 27 + 3 * k]     = sy;
            OMs[px * 27 + 3 * k + 1] = sx;
            OMs[px * 27 + 3 * k + 2] = mk;
        }
        __syncthreads();
    }

    // ============ phase 2: modulated deformable conv (GEMM N=64) ============
    f32x4 acc[4];
#pragma unroll
    for (int nt = 0; nt < 4; nt++) acc[nt] = (f32x4){0.f, 0.f, 0.f, 0.f};

    for (int kk = 0; kk < 9; kk += 2) {
#pragma unroll
        for (int u = 0; u < 2; u++) {
            int k = kk + u;
            if (k > 8) break;
            // two half-rounds of 2 rows (8 loads in flight) — pressure-safe at (256,6)
#pragma unroll
            for (int rp = 0; rp < 2; rp++) {
                int   idxs[2][4];
                float wvs[2][4];
#pragma unroll
                for (int rr = 0; rr < 2; rr++) {
                    int r = rp * 2 + rr;
                    int gpx = cb * 16 + r * 4 + pxo;
                    float sy = OMs[gpx * 27 + 3 * k];
                    float sx = OMs[gpx * 27 + 3 * k + 1];
                    float mk = OMs[gpx * 27 + 3 * k + 2];
                    float y0f = floorf(sy), x0f = floorf(sx);
                    int y0 = (int)y0f, x0 = (int)x0f;
                    float ty = sy - y0f, tx = sx - x0f;
#pragma unroll
                    for (int cr = 0; cr < 4; cr++) {
                        int dy = cr >> 1, dx = cr & 1;
                        int yy = y0 + dy, xx = x0 + dx;
                        float wy = dy ? ty : 1.f - ty;
                        float wx = dx ? tx : 1.f - tx;
                        bool vld = (yy >= 0) && (yy < H_) && (xx >= 0) && (xx < W_);
                        int yc = min(max(yy, 0), H_ - 1);
                        int xc = min(max(xx, 0), W_ - 1);
                        idxs[rr][cr] = yc * W_ + xc;
                        wvs[rr][cr]  = vld ? wy * wx * mk : 0.f;
                    }
                }
                u32x2 g[2][4];
#pragma unroll
                for (int rr = 0; rr < 2; rr++)
#pragma unroll
                    for (int cr = 0; cr < 4; cr++)
                        g[rr][cr] = *(const u32x2*)(xbh + (size_t)idxs[rr][cr] * 64 + chunk * 4);
#pragma unroll
                for (int rr = 0; rr < 2; rr++) {
                    int r = rp * 2 + rr;
                    int gpx = cb * 16 + r * 4 + pxo;
                    f32x4 v = (f32x4){0.f, 0.f, 0.f, 0.f};
#pragma unroll
                    for (int cr = 0; cr < 4; cr++) {
                        float wv = wvs[rr][cr];
                        float e0 = __uint_as_float(g[rr][cr].x << 16);
                        float e1 = __uint_as_float(g[rr][cr].x & 0xffff0000u);
                        float e2 = __uint_as_float(g[rr][cr].y << 16);
                        float e3 = __uint_as_float(g[rr][cr].y & 0xffff0000u);
                        v[0] = fmaf(e0, wv, v[0]);
                        v[1] = fmaf(e1, wv, v[1]);
                        v[2] = fmaf(e2, wv, v[2]);
                        v[3] = fmaf(e3, wv, v[3]);
                    }
                    unsigned int lo = ((unsigned int)f2bf(v[1]) << 16) | f2bf(v[0]);
                    unsigned int hi = ((unsigned int)f2bf(v[3]) << 16) | f2bf(v[2]);
                    *(u32x2*)(A_lds[u] + gpx * 72 + chunk * 4) = (u32x2){lo, hi};
                }
            }
        }

#pragma unroll
        for (int u = 0; u < 2; u++) {
            int k = kk + u;
            if (k > 8) break;
            const unsigned short* Ab = A_lds[u] + (cb * 16 + mrow) * 72;
#pragma unroll
            for (int ks = 0; ks < 2; ks++) {
                bf16x8 af = *(const bf16x8*)(Ab + ks * 32 + quad * 8);
#pragma unroll
                for (int nt = 0; nt < 4; nt++) {
                    bf16x8 bf_ = *(const bf16x8*)(wtb + k * 4608 + (nt * 16 + mrow) * 72 + ks * 32 + quad * 8);
                    acc[nt] = __builtin_amdgcn_mfma_f32_16x16x32_bf16(af, bf_, acc[nt], 0, 0, 0);
                }
            }
        }
    }

    // epilogue: C frag -> LDS [o][px pad65] -> NCHW store
    __syncthreads();
    float* C_lds = (float*)A_lds;
#pragma unroll
    for (int nt = 0; nt < 4; nt++) {
        int o = nt * 16 + mrow;
        int pxb = cb * 16 + quad * 4;
#pragma unroll
        for (int r = 0; r < 4; r++) C_lds[o * 65 + pxb + r] = acc[nt][r];
    }
    __syncthreads();
#pragma unroll
    for (int i = 0; i < 16; i++) {
        int o = cb * 16 + i;
        float v = C_lds[o * 65 + lane];
        v = fmaf(v, sb[o], sb[64 + o]);
        out[((size_t)b * 64 + o) * HW_ + p0 + lane] = fmaxf(v, 0.f);
    }
}

extern "C" void kernel_launch(void* const* d_in, const int* in_sizes, int n_in,
                              void* d_out, int out_size, void* d_ws, size_t ws_size,
                              hipStream_t stream)
{
    const float* f0 = (const float*)d_in[0];
    const float* f1 = (const float*)d_in[1];
    const float* f2 = (const float*)d_in[2];
    const float* f3 = (const float*)d_in[3];
    const float* w0 = (const float*)d_in[4];
    const float* g0 = (const float*)d_in[5];
    const float* b0 = (const float*)d_in[6];
    const float* m0 = (const float*)d_in[7];
    const float* v0 = (const float*)d_in[8];
    const float* w1 = (const float*)d_in[9];
    const float* g1 = (const float*)d_in[10];
    const float* b1 = (const float*)d_in[11];
    const float* m1 = (const float*)d_in[12];
    const float* v1 = (const float*)d_in[13];
    const float* w2 = (const float*)d_in[14];
    const float* g2 = (const float*)d_in[15];
    const float* b2 = (const float*)d_in[16];
    const float* m2 = (const float*)d_in[17];
    const float* v2 = (const float*)d_in[18];
    const float* w3 = (const float*)d_in[19];
    const float* g3 = (const float*)d_in[20];
    const float* b3 = (const float*)d_in[21];
    const float* m3 = (const float*)d_in[22];
    const float* v3 = (const float*)d_in[23];
    const float* off_w = (const float*)d_in[24];
    const float* off_b = (const float*)d_in[25];
    const float* dcn_w = (const float*)d_in[26];
    const float* gf = (const float*)d_in[27];
    const float* bf = (const float*)d_in[28];
    const float* mf = (const float*)d_in[29];
    const float* vf = (const float*)d_in[30];

    float* ws  = (float*)d_ws;
    float* out = (float*)d_out;

    prep_kernel<<<dim3(476), dim3(256), 0, stream>>>(
        g0, b0, m0, v0, g1, b1, m1, v1, g2, b2, m2, v2, g3, b3, m3, v3,
        gf, bf, mf, vf, w0, w1, w2, w3, dcn_w, off_w, ws);

    conv_all_kernel<<<dim3(525), dim3(256), 0, stream>>>(f1, f2, f3, ws);

    fuse_kernel<<<dim3(1600), dim3(256), 0, stream>>>(f0, ws);

    dcn_fused_kernel<<<dim3(1600), dim3(256), 0, stream>>>(off_b, ws, out);
}